// Round 3
// baseline (253.349 us; speedup 1.0000x reference)
//
#include <hip/hip_runtime.h>

#define BDIM 16
#define HSZ 64
#define NHEAD 16
#define LOG2E 1.4426950408889634f

typedef __bf16 bf16x8 __attribute__((ext_vector_type(8)));
typedef float f32x4 __attribute__((ext_vector_type(4)));
typedef float f32x2 __attribute__((ext_vector_type(2)));
typedef unsigned short us8 __attribute__((ext_vector_type(8)));
typedef unsigned int u32;

__device__ __forceinline__ unsigned short f2bf(float f) {
    u32 u = __float_as_uint(f);
    return (unsigned short)((u + 0x7fffu + ((u >> 16) & 1u)) >> 16);
}

__device__ __forceinline__ void gload_lds16(const void* g, void* l) {
    __builtin_amdgcn_global_load_lds(
        (const __attribute__((address_space(1))) void*)g,
        (__attribute__((address_space(3))) void*)l, 16, 0, 0);
}

// grid barrier: monotonic counter, device-scope. All 256 blocks co-resident
// (grid == CU count, __launch_bounds__(512,2) -> 1 block/CU guaranteed).
__device__ __forceinline__ void gsync(unsigned* bar, unsigned target) {
    __syncthreads();
    if (threadIdx.x == 0) {
        __hip_atomic_fetch_add(bar, 1u, __ATOMIC_ACQ_REL, __HIP_MEMORY_SCOPE_AGENT);
        while (__hip_atomic_load(bar, __ATOMIC_ACQUIRE, __HIP_MEMORY_SCOPE_AGENT) < target) {
            __builtin_amdgcn_s_sleep(8);
        }
    }
    __syncthreads();
}

// ---- 8-wave GEMM tile: C[BM=128 x BN=64] = A @ Bw^T + bias, BK=64 dbuf ----
// wave tile 32x32 (wr=w&3 row-quad, wc=w>>2 col-half), acc[2][2].
// mode 0: fp32 C (ldc=N). mode 1: bn<256 -> fp32 disp (ldc=256);
//         bn>=256 -> bf16 valT[(b*1024+col-256)*1024+t] via LDS transpose.
__device__ __forceinline__ void gemm_tile(
    unsigned char* smem, const unsigned short* __restrict__ A,
    const unsigned short* __restrict__ Bw, const float* __restrict__ bias,
    float* __restrict__ C, unsigned short* __restrict__ CbT,
    int N, int K, int bm, int bn, int mode, int tid) {
    unsigned short* lA = (unsigned short*)smem;            // [2][16*512] us
    unsigned short* lB = (unsigned short*)(smem + 32768);  // [2][8*512] us
    int w = tid >> 6, lane = tid & 63;
    int wr = w & 3, wc = w >> 2;
    int m16 = lane & 15, q = lane >> 4;

    __syncthreads();   // protect smem from previous stage/pass use

    // A granule g(0..15): rows (g&7)*16, k-block g>>3. B granule g(0..7):
    // cols (g&3)*16, k-block g>>2. granule = 16 rows x 32 k, [q][m16][8].
    int ga0 = w, ga1 = w + 8;
    const unsigned short* aPtr0 = A + (long)(bm + (ga0 & 7) * 16 + m16) * K + (ga0 >> 3) * 32 + q * 8;
    const unsigned short* aPtr1 = A + (long)(bm + (ga1 & 7) * 16 + m16) * K + (ga1 >> 3) * 32 + q * 8;
    const unsigned short* bPtr  = Bw + (long)(bn + (w & 3) * 16 + m16) * K + (w >> 2) * 32 + q * 8;

    f32x4 acc[2][2];
#pragma unroll
    for (int r = 0; r < 2; ++r)
#pragma unroll
        for (int n = 0; n < 2; ++n) acc[r][n] = (f32x4){0.f, 0.f, 0.f, 0.f};

    int nk = K >> 6;
    gload_lds16(aPtr0, &lA[ga0 * 512]);
    gload_lds16(aPtr1, &lA[ga1 * 512]);
    gload_lds16(bPtr, &lB[w * 512]);

    for (int kt = 0; kt < nk; ++kt) {
        int p = kt & 1;
        __syncthreads();
        if (kt + 1 < nk) {
            int ko = (kt + 1) * 64;
            gload_lds16(aPtr0 + ko, &lA[(p ^ 1) * 8192 + ga0 * 512]);
            gload_lds16(aPtr1 + ko, &lA[(p ^ 1) * 8192 + ga1 * 512]);
            gload_lds16(bPtr + ko, &lB[(p ^ 1) * 4096 + w * 512]);
        }
#pragma unroll
        for (int s = 0; s < 2; ++s) {
            bf16x8 af[2], bg[2];
#pragma unroll
            for (int r = 0; r < 2; ++r)
                af[r] = *(const bf16x8*)&lA[p * 8192 + (s * 8 + wr * 2 + r) * 512 + lane * 8];
#pragma unroll
            for (int n = 0; n < 2; ++n)
                bg[n] = *(const bf16x8*)&lB[p * 4096 + (s * 4 + wc * 2 + n) * 512 + lane * 8];
#pragma unroll
            for (int r = 0; r < 2; ++r)
#pragma unroll
                for (int n = 0; n < 2; ++n)
                    acc[r][n] = __builtin_amdgcn_mfma_f32_16x16x32_bf16(af[r], bg[n], acc[r][n], 0, 0, 0);
        }
    }

    if (mode == 0 || bn < 256) {
        int ldc = (mode == 0) ? N : 256;
#pragma unroll
        for (int n = 0; n < 2; ++n) {
            int col = bn + wc * 32 + n * 16 + m16;
            float bv = bias[col];
#pragma unroll
            for (int r = 0; r < 2; ++r)
#pragma unroll
                for (int e = 0; e < 4; ++e) {
                    int row = bm + wr * 32 + r * 16 + q * 4 + e;
                    C[(long)row * ldc + col] = acc[r][n][e] + bv;
                }
        }
    } else {
        __syncthreads();
        unsigned short* sC = lA;   // 128 x 64 bf16
#pragma unroll
        for (int n = 0; n < 2; ++n) {
            int col_l = wc * 32 + n * 16 + m16;
            float bv = bias[bn + col_l];
#pragma unroll
            for (int r = 0; r < 2; ++r)
#pragma unroll
                for (int e = 0; e < 4; ++e) {
                    int row_l = wr * 32 + r * 16 + q * 4 + e;
                    sC[row_l * 64 + col_l] = f2bf(acc[r][n][e] + bv);
                }
        }
        __syncthreads();
        long base0 = ((long)(bm >> 10)) * 1048576 + (long)(bn - 256) * 1024 + (bm & 1023);
#pragma unroll
        for (int it = 0; it < 2; ++it) {
            int slot = it * 512 + tid;   // 1024 slots = 64 hs x 16 t-chunks
            int hs = slot >> 4;
            int tc = (slot & 15) * 8;
            us8 o;
#pragma unroll
            for (int j = 0; j < 8; ++j) o[j] = sC[(tc + j) * 64 + hs];
            *(us8*)&CbT[base0 + (long)hs * 1024 + tc] = o;
        }
    }
}

// packed 2-wide gelu, Pade(1,1) tanh (|u|<~0.5 -> err ~1e-3, << threshold)
__device__ __forceinline__ f32x2 gelu2(f32x2 z) {
    f32x2 z2 = z * z;
    f32x2 u = z * (0.7978845608f + 0.0356774081f * z2);
    f32x2 u2 = u * u;
    f32x2 den = 1.f + 0.33333333f * u2;
    f32x2 r;
    r.x = __builtin_amdgcn_rcpf(den.x);
    r.y = __builtin_amdgcn_rcpf(den.y);
    f32x2 th = u * r;
    f32x2 zh = 0.5f * z;
    return zh + zh * th;
}

#define PROJ_LD 36
#define VW_LD 136

// one attn tile = (b, h, 64-t rows). 512 threads / 8 waves. T=1024 fixed.
__device__ __forceinline__ void attn_tile(
    unsigned char* smem, const float* __restrict__ disp,
    const unsigned short* __restrict__ valT, const float* __restrict__ rel,
    const float* __restrict__ Wpos, const float* __restrict__ Wf,
    const float* __restrict__ bfu, const float* __restrict__ Wb,
    const float* __restrict__ bb_p, const float* __restrict__ Wd,
    const float* __restrict__ bd_p, unsigned short* __restrict__ y,
    int tile, int tid) {
    const int T = 1024;
    unsigned short* sWd = (unsigned short*)smem;       // [64][136] bf16
    float* ov = (float*)(smem + 17408);                // 28672 B
    float* sProj = ov;                                 // [128][36]
    float* sDisp = ov + 128 * PROJ_LD;                 // [128][16]
    float* sWfT  = sDisp + 128 * 16;                   // [16][32]
    unsigned short* sValT = (unsigned short*)ov;       // phase D overlay [64][136]

    int t0 = (tile & 15) * 64;
    int bh = tile >> 4;
    int b = bh >> 4, h = bh & 15;
    int wave = tid >> 6, lane = tid & 63;
    int m16 = lane & 15, q = lane >> 4;

    __syncthreads();   // protect smem from previous use

    // ---- Phase A: zero sWd, stage WfT + disp, compute proj ----
    {
        uint4 z4 = make_uint4(0, 0, 0, 0);
        for (int i = tid; i < 1088; i += 512) ((uint4*)sWd)[i] = z4;
        sWfT[(tid & 15) * 32 + (tid >> 4)] = Wf[tid];
        {
            int r = tid >> 2, qq = tid & 3;
            int ts = t0 + r - 64;
            float4 v = make_float4(0.f, 0.f, 0.f, 0.f);
            if (ts >= 0)
                v = ((const float4*)(disp + ((long)(b * T + ts) * NHEAD + h) * BDIM))[qq];
            *(float4*)&sDisp[r * 16 + qq * 4] = v;
        }
    }
    __syncthreads();
    for (int idx = tid; idx < 128 * 32; idx += 512) {
        int r = idx >> 5, k = idx & 31;
        float a = 0.f;
#pragma unroll
        for (int d = 0; d < 16; ++d) a += sDisp[r * 16 + d] * sWfT[d * 32 + k];
        sProj[r * PROJ_LD + k] = a;
    }

    // lane-constant params (lane == j)
    float relv[16];
#pragma unroll
    for (int e = 0; e < 4; ++e) {
        float4 rr = ((const float4*)rel)[lane * 4 + e];
        relv[e * 4 + 0] = rr.x; relv[e * 4 + 1] = rr.y;
        relv[e * 4 + 2] = rr.z; relv[e * 4 + 3] = rr.w;
    }
    f32x2 pfd[16], wbd[16];
#pragma unroll
    for (int d = 0; d < 16; ++d) {
        float a = 0.f;
#pragma unroll
        for (int e = 0; e < 16; ++e) a += relv[e] * Wpos[d * 16 + e];
        pfd[d].x = a + bfu[d];
        pfd[d].y = bfu[16 + d];
        wbd[d].x = Wb[d];
        wbd[d].y = Wd[d];
    }
    float bbond = *bb_p, bdmg = *bd_p;
    __syncthreads();

    // ---- Phase B: logits + softmax (no max-shift; |logit|<~1) ----
    int wbase = wave * 8;
    for (int rr = 0; rr < 8; ++rr) {
        int tl = wbase + rr;
        int rs = tl + 1 + lane;
        int rc = tl + 64;
        bool valid = (t0 + tl + lane - 63) >= 0;
        float cb[16], cd[16], pb[16], pd[16];
        const float* crow = &sProj[rc * PROJ_LD];
        const float* prow = &sProj[rs * PROJ_LD];
#pragma unroll
        for (int qq = 0; qq < 4; ++qq) {
            float4 v1 = *(const float4*)&crow[qq * 4];
            float4 v2 = *(const float4*)&crow[16 + qq * 4];
            float4 v3 = *(const float4*)&prow[qq * 4];
            float4 v4 = *(const float4*)&prow[16 + qq * 4];
            cb[qq*4+0]=v1.x; cb[qq*4+1]=v1.y; cb[qq*4+2]=v1.z; cb[qq*4+3]=v1.w;
            cd[qq*4+0]=v2.x; cd[qq*4+1]=v2.y; cd[qq*4+2]=v2.z; cd[qq*4+3]=v2.w;
            pb[qq*4+0]=v3.x; pb[qq*4+1]=v3.y; pb[qq*4+2]=v3.z; pb[qq*4+3]=v3.w;
            pd[qq*4+0]=v4.x; pd[qq*4+1]=v4.y; pd[qq*4+2]=v4.z; pd[qq*4+3]=v4.w;
        }
        f32x2 acc2 = (f32x2){bbond, bdmg};
#pragma unroll
        for (int k = 0; k < 16; ++k) {
            f32x2 pz, cz;
            pz.x = pb[k]; pz.y = pd[k];
            cz.x = cb[k]; cz.y = cd[k];
            f32x2 z = pz - cz + pfd[k];
            acc2 = acc2 + gelu2(z) * wbd[k];
        }
        float bl = acc2.x, dm = acc2.y;
        float damage = __builtin_amdgcn_rcpf(1.f + __builtin_exp2f(-dm * LOG2E));
        float logit = bl - 10.f * damage;
        float e = valid ? __builtin_exp2f(logit * LOG2E) : 0.f;
        float ssum = e;
#pragma unroll
        for (int off = 32; off >= 1; off >>= 1) ssum += __shfl_xor(ssum, off);
        sWd[tl * VW_LD + rs] = f2bf(e * __builtin_amdgcn_rcpf(ssum));
    }
    __syncthreads();

    // ---- stage sValT[hs][r'] (overlays ov) ----
    {
        int hs = lane;
        long vbase = ((long)(b * NHEAD * HSZ + h * HSZ + hs)) * T + (t0 - 64);
#pragma unroll
        for (int it = 0; it < 2; ++it) {
            int g = wave * 2 + it;
            int ts0 = t0 - 64 + g * 8;
            us8 v = (us8)0;
            if (ts0 >= 0) v = *(const us8*)&valT[vbase + g * 8];
            *(us8*)&sValT[hs * VW_LD + g * 8] = v;
        }
    }
    __syncthreads();

    // ---- Phase D: out[t][hs] = sum_r sWd[t][r] * sValT[hs][r] via MFMA ----
    {
        int mi = wave >> 1;
        int nh = (wave & 1) * 2;
        int kt0 = mi >> 1;
        f32x4 acc[2];
#pragma unroll
        for (int n = 0; n < 2; ++n) acc[n] = (f32x4){0.f, 0.f, 0.f, 0.f};
#pragma unroll
        for (int kk = 0; kk < 3; ++kk) {
            int kt = kt0 + kk;
            bf16x8 a = *(const bf16x8*)&sWd[(mi * 16 + m16) * VW_LD + kt * 32 + q * 8];
#pragma unroll
            for (int n = 0; n < 2; ++n) {
                bf16x8 bv = *(const bf16x8*)&sValT[((nh + n) * 16 + m16) * VW_LD + kt * 32 + q * 8];
                acc[n] = __builtin_amdgcn_mfma_f32_16x16x32_bf16(a, bv, acc[n], 0, 0, 0);
            }
        }
        int trow = t0 + mi * 16 + q * 4;
#pragma unroll
        for (int n = 0; n < 2; ++n) {
            int col = h * HSZ + (nh + n) * 16 + m16;
#pragma unroll
            for (int e = 0; e < 4; ++e)
                y[(long)(b * T + trow + e) * (NHEAD * HSZ) + col] = f2bf(acc[n][e]);
        }
    }
}

// ---- persistent fused kernel: cast -> gemm1 -> attn -> gemm2 ----
// grid = 256 = CU count, 512 thr, 1 block/CU co-resident.
__global__ __launch_bounds__(512, 2) void fused_all(
    const float* __restrict__ x, const float* __restrict__ Wd_w,
    const float* __restrict__ bdp, const float* __restrict__ Wv_w,
    const float* __restrict__ bvp, const float* __restrict__ rel,
    const float* __restrict__ Wf, const float* __restrict__ bfu,
    const float* __restrict__ Wpos, const float* __restrict__ Wb,
    const float* __restrict__ bb_p, const float* __restrict__ Wdm,
    const float* __restrict__ bd_p, const float* __restrict__ Wc_w,
    const float* __restrict__ bc, float* __restrict__ out,
    float* __restrict__ disp, float* __restrict__ bcat,
    unsigned short* __restrict__ x_bf, unsigned short* __restrict__ valT,
    unsigned short* __restrict__ Wcat, unsigned short* __restrict__ Wv_bf,
    unsigned short* __restrict__ Wc_bf, unsigned short* __restrict__ y_bf,
    unsigned* bar) {
    __shared__ __align__(16) unsigned char smem[49152];
    int tid = threadIdx.x;
    int bid = blockIdx.x;

    // ---- stage 0: fp32->bf16 casts (grid-stride) + bias concat ----
    {
        int gid = bid * 512 + tid;
        for (int i = gid; i < 1114112; i += 131072) {
            const float* src; unsigned short* dst; int j;
            if (i < 524288)      { src = x;    dst = x_bf;  j = i; }
            else if (i < 589824) { src = Wd_w; dst = Wcat;  j = i - 524288; }
            else if (i < 851968) { src = Wv_w; dst = Wv_bf; j = i - 589824; }
            else                 { src = Wc_w; dst = Wc_bf; j = i - 851968; }
            float4 f = ((const float4*)src)[j];
            ushort4 o;
            o.x = f2bf(f.x); o.y = f2bf(f.y); o.z = f2bf(f.z); o.w = f2bf(f.w);
            ((ushort4*)dst)[j] = o;
        }
        if (bid == 255 && tid < 320) {
            if (tid < 64) ((float4*)bcat)[tid] = ((const float4*)bdp)[tid];
            else          ((float4*)bcat)[tid] = ((const float4*)bvp)[tid - 64];
        }
    }
    gsync(bar, 256);

    // ---- stage 1: gemm1 (disp | valT), 320 tiles of 128x64, N=1280 ----
    {
        int mi = bid & 15, ni = bid >> 4;
        gemm_tile(smem, x_bf, Wcat, bcat, disp, valT, 1280, 1024,
                  mi * 128, ni * 64, 1, tid);
        if (bid < 64) {
            int t2 = 256 + bid;
            gemm_tile(smem, x_bf, Wcat, bcat, disp, valT, 1280, 1024,
                      (t2 & 15) * 128, (t2 >> 4) * 64, 1, tid);
        }
    }
    gsync(bar, 512);

    // ---- stage 2: attn, 512 tiles, 2 per block ----
    attn_tile(smem, disp, valT, rel, Wpos, Wf, bfu, Wb, bb_p, Wdm, bd_p,
              y_bf, bid, tid);
    attn_tile(smem, disp, valT, rel, Wpos, Wf, bfu, Wb, bb_p, Wdm, bd_p,
              y_bf, bid + 256, tid);
    gsync(bar, 768);

    // ---- stage 3: gemm2 (out = y @ Wc^T + bc), 256 tiles of 128x64 ----
    {
        int mi = bid & 15, ni = bid >> 4;
        gemm_tile(smem, y_bf, Wc_bf, bc, out, nullptr, 1024, 1024,
                  mi * 128, ni * 64, 0, tid);
    }
}

extern "C" void kernel_launch(void* const* d_in, const int* in_sizes, int n_in,
                              void* d_out, int out_size, void* d_ws, size_t ws_size,
                              hipStream_t stream) {
    const float* x       = (const float*)d_in[0];
    const float* W_disp  = (const float*)d_in[1];
    const float* b_disp  = (const float*)d_in[2];
    const float* W_val   = (const float*)d_in[3];
    const float* b_val   = (const float*)d_in[4];
    const float* rel     = (const float*)d_in[5];
    const float* W_fused = (const float*)d_in[6];
    const float* b_fused = (const float*)d_in[7];
    const float* W_pos   = (const float*)d_in[8];
    const float* W_bond  = (const float*)d_in[9];
    const float* b_bond  = (const float*)d_in[10];
    const float* W_dmg   = (const float*)d_in[11];
    const float* b_dmg   = (const float*)d_in[12];
    const float* W_cproj = (const float*)d_in[13];
    const float* b_cproj = (const float*)d_in[14];
    float* out = (float*)d_out;
    float* ws  = (float*)d_ws;

    // workspace layout (~14.6 MB used; barrier at +32 MB, clean)
    float* disp = ws;                                        // 524288 f
    float* bcat = disp + 524288;                             // 1280 f
    unsigned short* x_bf  = (unsigned short*)(bcat + 1280);  // 2097152 us (= y_bf)
    unsigned short* valT  = x_bf + 2097152;                  // 2097152 us
    unsigned short* Wcat  = valT + 2097152;                  // 262144 us
    unsigned short* Wv_bf = Wcat + 262144;                   // 1048576 us
    unsigned short* Wc_bf = Wv_bf + 1048576;                 // 1048576 us
    unsigned short* y_bf  = x_bf;
    unsigned* bar = (unsigned*)((char*)d_ws + (32u << 20));

    hipMemsetAsync(bar, 0, 256, stream);   // barrier counter init (capturable)

    fused_all<<<256, 512, 0, stream>>>(
        x, W_disp, b_disp, W_val, b_val, rel, W_fused, b_fused, W_pos,
        W_bond, b_bond, W_dmg, b_dmg, W_cproj, b_cproj, out,
        disp, bcat, x_bf, valT, Wcat, Wv_bf, Wc_bf, y_bf, bar);
}

// Round 4
// 169.843 us; speedup vs baseline: 1.4917x; 1.4917x over previous
//
#include <hip/hip_runtime.h>

#define BDIM 16
#define HSZ 64
#define NHEAD 16
#define DELTA 64
#define LOG2E 1.4426950408889634f

typedef __bf16 bf16x8 __attribute__((ext_vector_type(8)));
typedef float f32x4 __attribute__((ext_vector_type(4)));
typedef float f32x2 __attribute__((ext_vector_type(2)));
typedef unsigned short us8 __attribute__((ext_vector_type(8)));
typedef unsigned int u32;

__device__ __forceinline__ unsigned short f2bf(float f) {
    u32 u = __float_as_uint(f);
    return (unsigned short)((u + 0x7fffu + ((u >> 16) & 1u)) >> 16);
}

__device__ __forceinline__ void gload_lds16(const void* g, void* l) {
    __builtin_amdgcn_global_load_lds(
        (const __attribute__((address_space(1))) void*)g,
        (__attribute__((address_space(3))) void*)l, 16, 0, 0);
}

// merged float->bf16 casts for x, W_disp, W_val, W_cproj + bias concat
__global__ __launch_bounds__(256) void cast4_bf16(
    const float* __restrict__ s0, unsigned short* __restrict__ d0,
    const float* __restrict__ s1, unsigned short* __restrict__ d1,
    const float* __restrict__ s2, unsigned short* __restrict__ d2,
    const float* __restrict__ s3, unsigned short* __restrict__ d3,
    const float* __restrict__ bd, const float* __restrict__ bv,
    float* __restrict__ bcat) {
    int blk = blockIdx.x;
    if (blk == 4352) {   // bias concat: 64 f4 from b_disp, 256 f4 from b_val
        for (int t = threadIdx.x; t < 320; t += 256) {
            if (t < 64) ((float4*)bcat)[t] = ((const float4*)bd)[t];
            else        ((float4*)bcat)[t] = ((const float4*)bv)[t - 64];
        }
        return;
    }
    const float* src; unsigned short* dst; int base;
    if (blk < 2048)      { src = s0; dst = d0; base = blk; }
    else if (blk < 2304) { src = s1; dst = d1; base = blk - 2048; }
    else if (blk < 3328) { src = s2; dst = d2; base = blk - 2304; }
    else                 { src = s3; dst = d3; base = blk - 3328; }
    int i = base * 256 + threadIdx.x;
    float4 f = ((const float4*)src)[i];
    ushort4 o;
    o.x = f2bf(f.x); o.y = f2bf(f.y); o.z = f2bf(f.z); o.w = f2bf(f.w);
    ((ushort4*)dst)[i] = o;
}

// C = A[M,K] @ Bw[N,K]^T + bias.  M = 2048 fixed (16 m-tiles of 128).
// mode 0: fp32 out C[M x N].
// mode 1: fused disp|val: cols<256 -> fp32 disp[M x 256]; cols>=256 -> bf16
//         valT[(b*1024 + col-256)*1024 + t] via LDS-bounce transpose.
// BM=128, BN=64, BK=64, 4 waves, wave tile 64x32 (acc 4x2).  [round-1 verbatim]
__global__ __launch_bounds__(256) void gemm_bf16(const unsigned short* __restrict__ A,
                                                 const unsigned short* __restrict__ Bw,
                                                 const float* __restrict__ bias,
                                                 float* __restrict__ C,
                                                 unsigned short* __restrict__ CbT,
                                                 int N, int K, int nbx, int mode) {
    __shared__ __align__(16) unsigned short lA[2][16 * 512];   // 128 x 64 per buf
    __shared__ __align__(16) unsigned short lB[2][8 * 512];    // 64 x 64 per buf
    int tid = threadIdx.x;
    int w = tid >> 6, lane = tid & 63;
    int id = blockIdx.x;
    int xcd = id & 7, rr = id >> 3;
    int mi = xcd * 2 + (rr & 1);      // 16 m-tiles, 2 per XCD
    int ni = rr >> 1;                 // 0..nbx-1
    int bm = mi * 128, bn = ni * 64;
    int wr = w & 1, wc = w >> 1;      // wave tile: rows wr*64, cols wc*32
    int m16 = lane & 15, q = lane >> 4;

    const unsigned short* aPtr[4];
    const unsigned short* bPtr[2];
#pragma unroll
    for (int i = 0; i < 4; ++i) {
        int g = w + 4 * i;
        aPtr[i] = A + (long)(bm + (g & 7) * 16 + m16) * K + (g >> 3) * 32 + q * 8;
    }
#pragma unroll
    for (int i = 0; i < 2; ++i) {
        int g = w + 4 * i;
        bPtr[i] = Bw + (long)(bn + (g & 3) * 16 + m16) * K + (g >> 2) * 32 + q * 8;
    }

    f32x4 acc[4][2];
#pragma unroll
    for (int i = 0; i < 4; ++i)
#pragma unroll
        for (int j = 0; j < 2; ++j) acc[i][j] = (f32x4){0.f, 0.f, 0.f, 0.f};

    int nk = K >> 6;
#pragma unroll
    for (int i = 0; i < 4; ++i) gload_lds16(aPtr[i], &lA[0][(w + 4 * i) * 512]);
#pragma unroll
    for (int i = 0; i < 2; ++i) gload_lds16(bPtr[i], &lB[0][(w + 4 * i) * 512]);

    for (int kt = 0; kt < nk; ++kt) {
        int p = kt & 1;
        __syncthreads();
        if (kt + 1 < nk) {
            int ko = (kt + 1) * 64;
#pragma unroll
            for (int i = 0; i < 4; ++i)
                gload_lds16(aPtr[i] + ko, &lA[p ^ 1][(w + 4 * i) * 512]);
#pragma unroll
            for (int i = 0; i < 2; ++i)
                gload_lds16(bPtr[i] + ko, &lB[p ^ 1][(w + 4 * i) * 512]);
        }
#pragma unroll
        for (int s = 0; s < 2; ++s) {
            bf16x8 af[4], bg[2];
#pragma unroll
            for (int r = 0; r < 4; ++r)
                af[r] = *(const bf16x8*)&lA[p][(s * 8 + wr * 4 + r) * 512 + lane * 8];
#pragma unroll
            for (int n = 0; n < 2; ++n)
                bg[n] = *(const bf16x8*)&lB[p][(s * 4 + wc * 2 + n) * 512 + lane * 8];
#pragma unroll
            for (int r = 0; r < 4; ++r)
#pragma unroll
                for (int n = 0; n < 2; ++n)
                    acc[r][n] = __builtin_amdgcn_mfma_f32_16x16x32_bf16(af[r], bg[n], acc[r][n], 0, 0, 0);
        }
    }

    if (mode == 0 || bn < 256) {
        int ldc = (mode == 0) ? N : 256;
#pragma unroll
        for (int n = 0; n < 2; ++n) {
            int col = bn + wc * 32 + n * 16 + m16;
            float bv = bias[col];
#pragma unroll
            for (int r = 0; r < 4; ++r)
#pragma unroll
                for (int e = 0; e < 4; ++e) {
                    int row = bm + wr * 64 + r * 16 + q * 4 + e;
                    C[(long)row * ldc + col] = acc[r][n][e] + bv;
                }
        }
    } else {
        // valT path: bounce through LDS; write remapped so each 8-lane group
        // stores 128B contiguous along t.
        __syncthreads();
        unsigned short* sC = (unsigned short*)&lA[0][0];   // 128 x 64
#pragma unroll
        for (int n = 0; n < 2; ++n) {
            int col_l = wc * 32 + n * 16 + m16;
            float bv = bias[bn + col_l];
#pragma unroll
            for (int r = 0; r < 4; ++r)
#pragma unroll
                for (int e = 0; e < 4; ++e) {
                    int row_l = wr * 64 + r * 16 + q * 4 + e;
                    sC[row_l * 64 + col_l] = f2bf(acc[r][n][e] + bv);
                }
        }
        __syncthreads();
        long base0 = ((long)(bm >> 10)) * 1048576 + (long)(bn - 256) * 1024 + (bm & 1023);
#pragma unroll
        for (int it = 0; it < 4; ++it) {
            int slot = it * 256 + tid;     // 1024 slots = 64 hs x 16 t-chunks
            int hs = (slot >> 3) & 63;
            int tc = (slot & 7) * 8 + (slot >> 9) * 64;
            us8 o;
#pragma unroll
            for (int j = 0; j < 8; ++j) o[j] = sC[(tc + j) * 64 + hs];
            *(us8*)&CbT[base0 + (long)hs * 1024 + tc] = o;
        }
    }
}

// packed 2-wide gelu, Pade(1,1) tanh (|u|<~0.5 -> err ~1e-3, << threshold)
__device__ __forceinline__ f32x2 gelu2(f32x2 z) {
    f32x2 z2 = z * z;
    f32x2 u = z * (0.7978845608f + 0.0356774081f * z2);
    f32x2 u2 = u * u;
    f32x2 den = 1.f + 0.33333333f * u2;
    f32x2 r;
    r.x = __builtin_amdgcn_rcpf(den.x);
    r.y = __builtin_amdgcn_rcpf(den.y);
    f32x2 th = u * r;
    f32x2 zh = 0.5f * z;
    return zh + zh * th;
}

#define PROJ_LD 36
#define SW_LD 104

// attn re-tile for latency-hiding (round-3 lesson: everything here is
// latency-bound; independent blocks/CU are the lever).
// One block per (b, h, 32-t tile): 256 threads / 4 waves, grid 1024 ->
// 4 independent barrier domains per CU (vs 2 before), LDS 28.7 KB (5 fit),
// __launch_bounds__(256,4). Per-row arithmetic identical to round-1.
__global__ __launch_bounds__(256, 4) void attn_kernel(
    const float* __restrict__ disp,             // (B,T,NH,BD) fp32
    const unsigned short* __restrict__ valT,    // (B, NH*HS, T) bf16
    const float* __restrict__ rel,              // (64,16)
    const float* __restrict__ Wpos,             // (16,16)
    const float* __restrict__ Wf,               // (32,16)
    const float* __restrict__ bfu,              // (32,)
    const float* __restrict__ Wb,               // (16,)
    const float* __restrict__ bb_p,             // scalar
    const float* __restrict__ Wd,               // (16,)
    const float* __restrict__ bd_p,             // scalar
    unsigned short* __restrict__ y,             // (B,T,C) bf16
    int T) {
    __shared__ __align__(16) unsigned short sWd[32 * SW_LD];   // 6656 B
    __shared__ __align__(16) float ov[96 * PROJ_LD + 96 * 16 + 512];  // 22016 B
    float* sProj = ov;                      // [96][36]
    float* sDisp = ov + 96 * PROJ_LD;       // [96][16]
    float* sWfT  = sDisp + 96 * 16;         // [16][32] transposed
    unsigned short* sValT = (unsigned short*)ov;   // phase C/D overlay [64][104]

    int tid = threadIdx.x;
    int t0 = (blockIdx.x & 31) * 32;        // 32 t-tiles of 32 rows
    int bh = blockIdx.x >> 5;
    int b = bh >> 4, h = bh & 15;
    int wave = tid >> 6, lane = tid & 63;
    int m16 = lane & 15, q = lane >> 4;

    // ---- Phase A: zero sWd, stage WfT + disp[96 rows], compute proj ----
    {
        uint4 z4 = make_uint4(0, 0, 0, 0);
        for (int i = tid; i < 416; i += 256) ((uint4*)sWd)[i] = z4;
        sWfT[(tid & 15) * 32 + (tid >> 4)] = Wf[tid];
        { int j = tid + 256; sWfT[(j & 15) * 32 + (j >> 4)] = Wf[j]; }
        for (int i = tid; i < 384; i += 256) {    // 96 rows x 4 quads
            int r = i >> 2, qq = i & 3;
            int ts = t0 + r - 64;
            float4 v = make_float4(0.f, 0.f, 0.f, 0.f);
            if (ts >= 0)
                v = ((const float4*)(disp + ((long)(b * T + ts) * NHEAD + h) * BDIM))[qq];
            *(float4*)&sDisp[r * 16 + qq * 4] = v;
        }
    }
    __syncthreads();
    for (int idx = tid; idx < 96 * 32; idx += 256) {
        int r = idx >> 5, k = idx & 31;
        float a = 0.f;
#pragma unroll
        for (int d = 0; d < 16; ++d) a += sDisp[r * 16 + d] * sWfT[d * 32 + k];
        sProj[r * PROJ_LD + k] = a;
    }

    // lane-constant params (lane == j)
    float relv[16];
#pragma unroll
    for (int e = 0; e < 4; ++e) {
        float4 rr = ((const float4*)rel)[lane * 4 + e];
        relv[e * 4 + 0] = rr.x; relv[e * 4 + 1] = rr.y;
        relv[e * 4 + 2] = rr.z; relv[e * 4 + 3] = rr.w;
    }
    f32x2 pfd[16], wbd[16];
#pragma unroll
    for (int d = 0; d < 16; ++d) {
        float a = 0.f;
#pragma unroll
        for (int e = 0; e < 16; ++e) a += relv[e] * Wpos[d * 16 + e];
        pfd[d].x = a + bfu[d];
        pfd[d].y = bfu[16 + d];
        wbd[d].x = Wb[d];
        wbd[d].y = Wd[d];
    }
    float bbond = *bb_p, bdmg = *bd_p;
    __syncthreads();

    // ---- Phase B: logits + softmax; 4 waves x 8 rows, lane = j ----
    // No max-shift (|logit| <~ 1, exp2 safe); masked lanes e=0, lane 63 valid.
    int wbase = wave * 8;
    for (int rr = 0; rr < 8; ++rr) {
        int tl = wbase + rr;
        int rs = tl + 1 + lane;       // window row in sProj (1..95)
        int rc = tl + 64;             // center row (64..95)
        bool valid = (t0 + tl + lane - 63) >= 0;
        float cb[16], cd[16], pb[16], pd[16];
        const float* crow = &sProj[rc * PROJ_LD];
        const float* prow = &sProj[rs * PROJ_LD];
#pragma unroll
        for (int qq = 0; qq < 4; ++qq) {
            float4 v1 = *(const float4*)&crow[qq * 4];
            float4 v2 = *(const float4*)&crow[16 + qq * 4];
            float4 v3 = *(const float4*)&prow[qq * 4];
            float4 v4 = *(const float4*)&prow[16 + qq * 4];
            cb[qq*4+0]=v1.x; cb[qq*4+1]=v1.y; cb[qq*4+2]=v1.z; cb[qq*4+3]=v1.w;
            cd[qq*4+0]=v2.x; cd[qq*4+1]=v2.y; cd[qq*4+2]=v2.z; cd[qq*4+3]=v2.w;
            pb[qq*4+0]=v3.x; pb[qq*4+1]=v3.y; pb[qq*4+2]=v3.z; pb[qq*4+3]=v3.w;
            pd[qq*4+0]=v4.x; pd[qq*4+1]=v4.y; pd[qq*4+2]=v4.z; pd[qq*4+3]=v4.w;
        }
        f32x2 acc2 = (f32x2){bbond, bdmg};
#pragma unroll
        for (int k = 0; k < 16; ++k) {
            f32x2 pz, cz;
            pz.x = pb[k]; pz.y = pd[k];
            cz.x = cb[k]; cz.y = cd[k];
            f32x2 z = pz - cz + pfd[k];
            acc2 = acc2 + gelu2(z) * wbd[k];
        }
        float bl = acc2.x, dm = acc2.y;
        float damage = __builtin_amdgcn_rcpf(1.f + __builtin_exp2f(-dm * LOG2E));
        float logit = bl - 10.f * damage;
        float e = valid ? __builtin_exp2f(logit * LOG2E) : 0.f;
        float ssum = e;
#pragma unroll
        for (int off = 32; off >= 1; off >>= 1) ssum += __shfl_xor(ssum, off);
        sWd[tl * SW_LD + rs] = f2bf(e * __builtin_amdgcn_rcpf(ssum));
    }
    __syncthreads();

    // ---- Phase C: stage sValT[hs][r'] (overlays ov); 64 hs x 12 granules ----
    for (int i = tid; i < 768; i += 256) {
        int g = i >> 6, hs = i & 63;    // wave-aligned: 64 consecutive i = one g
        int ts0 = t0 - 64 + g * 8;      // 8-aligned: all-or-nothing validity
        us8 v = (us8)0;
        if (ts0 >= 0)
            v = *(const us8*)&valT[((long)(b * NHEAD * HSZ + h * HSZ + hs)) * T + ts0];
        *(us8*)&sValT[hs * SW_LD + g * 8] = v;
    }
    __syncthreads();

    // ---- Phase D: out[t][hs] = sum_r sWd[t][r] * sValT[hs][r] via MFMA ----
    {
        int mi = wave & 1;              // t-tile (2 x 16 rows)
        int nh = (wave >> 1) * 2;       // hs-tile pair (4 x 16 cols)
        f32x4 acc[2];
#pragma unroll
        for (int n = 0; n < 2; ++n) acc[n] = (f32x4){0.f, 0.f, 0.f, 0.f};
#pragma unroll
        for (int kt = 0; kt < 3; ++kt) {   // k = 0..95 covers window 1..95
            bf16x8 a = *(const bf16x8*)&sWd[(mi * 16 + m16) * SW_LD + kt * 32 + q * 8];
#pragma unroll
            for (int n = 0; n < 2; ++n) {
                bf16x8 bv = *(const bf16x8*)&sValT[((nh + n) * 16 + m16) * SW_LD + kt * 32 + q * 8];
                acc[n] = __builtin_amdgcn_mfma_f32_16x16x32_bf16(a, bv, acc[n], 0, 0, 0);
            }
        }
        int trow = t0 + mi * 16 + q * 4;
#pragma unroll
        for (int n = 0; n < 2; ++n) {
            int col = h * HSZ + (nh + n) * 16 + m16;
#pragma unroll
            for (int e = 0; e < 4; ++e)
                y[(long)(b * T + trow + e) * (NHEAD * HSZ) + col] = f2bf(acc[n][e]);
        }
    }
}

extern "C" void kernel_launch(void* const* d_in, const int* in_sizes, int n_in,
                              void* d_out, int out_size, void* d_ws, size_t ws_size,
                              hipStream_t stream) {
    const float* x       = (const float*)d_in[0];
    const float* W_disp  = (const float*)d_in[1];
    const float* b_disp  = (const float*)d_in[2];
    const float* W_val   = (const float*)d_in[3];
    const float* b_val   = (const float*)d_in[4];
    const float* rel     = (const float*)d_in[5];
    const float* W_fused = (const float*)d_in[6];
    const float* b_fused = (const float*)d_in[7];
    const float* W_pos   = (const float*)d_in[8];
    const float* W_bond  = (const float*)d_in[9];
    const float* b_bond  = (const float*)d_in[10];
    const float* W_dmg   = (const float*)d_in[11];
    const float* b_dmg   = (const float*)d_in[12];
    const float* W_cproj = (const float*)d_in[13];
    const float* b_cproj = (const float*)d_in[14];
    float* out = (float*)d_out;
    float* ws  = (float*)d_ws;

    const int B = 2, T = 1024, C = 1024;
    // workspace layout
    float* disp = ws;                                        // 524288 f
    float* bcat = disp + 524288;                             // 1280 f
    unsigned short* x_bf  = (unsigned short*)(bcat + 1280);  // 2097152 us (reused as y_bf)
    unsigned short* valT  = x_bf + 2097152;                  // 2097152 us
    unsigned short* Wcat  = valT + 2097152;                  // 262144 us
    unsigned short* Wv_bf = Wcat + 262144;                   // 1048576 us
    unsigned short* Wc_bf = Wv_bf + 1048576;                 // 1048576 us
    unsigned short* y_bf  = x_bf;

    cast4_bf16<<<4353, 256, 0, stream>>>(x, x_bf, W_disp, Wcat, W_val, Wv_bf,
                                         W_cproj, Wc_bf, b_disp, b_val, bcat);

    // fused disp|val GEMM: N = 1280, grid 16 m-tiles x 20 n-tiles = 320
    gemm_bf16<<<320, 256, 0, stream>>>(x_bf, Wcat, bcat, disp, valT,
                                       1280, C, 20, 1);
    // attn: 32-row tiles, 4 blocks/CU
    attn_kernel<<<dim3(B * NHEAD * (T / 32)), 256, 0, stream>>>(
        disp, valT, rel, W_pos, W_fused, b_fused, W_bond, b_bond, W_dmg, b_dmg,
        y_bf, T);
    // out = y @ W_cproj^T + b_cproj (fp32), grid 16 x 16 = 256
    gemm_bf16<<<256, 256, 0, stream>>>(y_bf, Wc_bf, b_cproj, out, nullptr,
                                       C, C, 16, 0);
}